// Round 5
// baseline (4719.143 us; speedup 1.0000x reference)
//
#include <hip/hip_runtime.h>
#include <stdint.h>

// Problem constants
#define Bb   4
#define Tt   32
#define Cc   132
#define Nn   512
#define HID  256
#define KNB  16
#define OUTC 260           // 4 + HID
#define G4   1024          // 4*HID gate rows
#define KP   160           // padded K for P-gemm (132 -> 160, 5 chunks of 32)
#define ALD  132           // A LDS row stride (128 + 4 pad)
#define BLD  128           // B LDS row stride (must be 128: global_load_lds linear)

// Workspace layout (element counts)
#define WP_SZ (1024*KP)          // 163840 f
#define GI_SZ (Bb*Tt*Nn*KNB)     // 1048576 i
#define HT_SZ (Bb*HID*Nn)        // 524288 f
#define CB_SZ (Bb*Nn*HID)        // 524288 f
#define PQ_SZ (Bb*Nn*G4)         // 2097152 f

// Output offsets (floats): layer_output, h_f, c_f, group_ind
#define OFF_HF 17039360
#define OFF_CF 17563648
#define OFF_GI 18087936

// ---------------------------------------------------------------------------
__global__ __launch_bounds__(256) void init_kernel(const float* __restrict__ w,
                                                   float* __restrict__ WP,
                                                   float* __restrict__ hT,
                                                   float* __restrict__ c0) {
  int i = blockIdx.x * 256 + threadIdx.x;
  if (i < WP_SZ) {
    int o = i / KP, c = i % KP;
    float v = 0.f;
    if (c < Cc) {
      v = w[(size_t)o * 392 + c];
      if (c < 4) v -= w[(size_t)o * 392 + 132 + c];
    }
    WP[i] = v;
  } else if (i < WP_SZ + HT_SZ) {
    hT[i - WP_SZ] = 0.f;
  } else if (i < WP_SZ + HT_SZ + CB_SZ) {
    c0[i - WP_SZ - HT_SZ] = 0.f;
  }
}

// ---------------------------------------------------------------------------
// KNN v3: same arithmetic & merge semantics as the R2 kernel (proven exact),
// with conflict-free LDS layouts:
//  - r arrays padded by m>>7 so the 4 candidate-subranges read distinct banks
//    (scan order within each sub UNCHANGED -> tie semantics preserved)
//  - blists [sub][ql][17] pad -> 4-way max on writes, 0-conflict merge reads
__global__ __launch_bounds__(256) void knn_kernel(const float* __restrict__ x,
                                                  int* __restrict__ gi,
                                                  float* __restrict__ gi_f) {
  int bt = blockIdx.x >> 3;
  int b = bt >> 5, t = bt & 31;
  int q0 = (blockIdx.x & 7) << 6;
  int tr = t > 0 ? t - 1 : 0;
  __shared__ float r0[516], r1[516], r2[516], rr[516];
  __shared__ unsigned long long blists[4][64][17];  // ~34.8 KB
  const float* xr = x + (size_t)(b * Tt + tr) * Cc * Nn;
  for (int m = threadIdx.x; m < Nn; m += 256) {
    int mi = m + (m >> 7);
    float a0 = xr[m], a1 = xr[Nn + m], a2 = xr[2 * Nn + m];
    r0[mi] = a0; r1[mi] = a1; r2[mi] = a2;
    rr[mi] = __fadd_rn(__fadd_rn(__fmul_rn(a0, a0), __fmul_rn(a1, a1)), __fmul_rn(a2, a2));
  }
  __syncthreads();
  int ql = threadIdx.x >> 2;
  int sub = threadIdx.x & 3;
  int n = q0 + ql;
  const float* xq = x + (size_t)(b * Tt + t) * Cc * Nn;
  float q0v = xq[n], q1v = xq[Nn + n], q2v = xq[2 * Nn + n];
  float qq = __fadd_rn(__fadd_rn(__fmul_rn(q0v, q0v), __fmul_rn(q1v, q1v)), __fmul_rn(q2v, q2v));
  float bd[KNB];
  int bi[KNB];
#pragma unroll
  for (int s = 0; s < KNB; ++s) { bd[s] = __int_as_float(0x7F800000); bi[s] = 0; }
  const int m0 = sub << 7;
  const int mb = m0 + sub;          // padded base: (m0+mm) + ((m0+mm)>>7) = mb+mm
  for (int mm = 0; mm < 128; ++mm) {
    int m = m0 + mm;
    int mi = mb + mm;
    float in = __fmaf_rn(q2v, r2[mi], __fmaf_rn(q1v, r1[mi], __fmul_rn(q0v, r0[mi])));
    float cd = __fsub_rn(__fadd_rn(qq, rr[mi]), __fmul_rn(2.0f, in));
    int ci = m;
#pragma unroll
    for (int s = 0; s < KNB; ++s) {
      bool sw = cd < bd[s];
      float td = sw ? bd[s] : cd;
      int ti = sw ? bi[s] : ci;
      bd[s] = sw ? cd : bd[s];
      bi[s] = sw ? ci : bi[s];
      cd = td; ci = ti;
    }
  }
#pragma unroll
  for (int s = 0; s < KNB; ++s) {
    unsigned int bits = __float_as_uint(bd[s]);
    unsigned int key = (bits & 0x80000000u) ? ~bits : (bits | 0x80000000u);
    blists[sub][ql][s] = ((unsigned long long)key << 32) | (unsigned int)bi[s];
  }
  __syncthreads();
  if (sub == 0) {
    int p0 = 0, p1 = 0, p2 = 0, p3 = 0;
    size_t ob = ((size_t)(b * Tt + t) * Nn + n) * KNB;
#pragma unroll
    for (int s = 0; s < KNB; ++s) {
      unsigned long long h0 = blists[0][ql][p0 & 15];
      unsigned long long h1 = blists[1][ql][p1 & 15];
      unsigned long long h2 = blists[2][ql][p2 & 15];
      unsigned long long h3 = blists[3][ql][p3 & 15];
      unsigned long long mv = h0; int ml = 0;
      if (h1 < mv) { mv = h1; ml = 1; }
      if (h2 < mv) { mv = h2; ml = 2; }
      if (h3 < mv) { mv = h3; ml = 3; }
      p0 += (ml == 0); p1 += (ml == 1); p2 += (ml == 2); p3 += (ml == 3);
      int idx = (int)(mv & 0xFFFFFFFFull);
      gi[ob + s] = idx;
      gi_f[ob + s] = (float)idx;
    }
  }
}

// ---------------------------------------------------------------------------
__device__ __forceinline__ void async_cp16(const float* g, float* l) {
  __builtin_amdgcn_global_load_lds((const __attribute__((address_space(1))) void*)g,
                                   (__attribute__((address_space(3))) void*)l, 16, 0, 0);
}

// 128x128-tile fp32 GEMM, 256 threads, 8x8 micro, double-buffered LDS chunks.
// Per-output-element FMA chain identical to the R1/R2 kernels (bias init,
// ascending K, zero-padded tails) -> bitwise identical results.
template <bool QM>
__device__ __forceinline__ void gemm_tile_v3(int bid, int tstep,
                                             const float* __restrict__ x,
                                             const float* __restrict__ w,
                                             const float* __restrict__ WP,
                                             const float* __restrict__ hT,
                                             const float* __restrict__ bias,
                                             float* __restrict__ outp,
                                             float* Abuf, float* Bbuf) {
  const int b = bid >> 5;
  const int to = (bid >> 2) & 7;
  const int tn = bid & 3;
  const int o0 = to << 7, n0 = tn << 7;
  const int tid = threadIdx.x;
  const int tx = tid & 15, ty = tid >> 4;
  const int tp = (tstep > 0) ? tstep - 1 : 0;
  const int nch = QM ? 9 : 5;
  // A staging mapping (same as R1)
  const int acb = (tid & 7) * 4;   // c offset within chunk
  const int aor = tid >> 3;        // o row (0..31, +p*32)
  // B staging mapping: row cc = (tid>>5)+8p, col floats (tid&31)*4.
  // LDS byte offset = 4096p + 1024*wave + 16*lane  -> wave-linear for DMA.
  const int bcol = (tid & 31) * 4;
  const int brow = tid >> 5;
  const int wvf = ((tid >> 6) << 8);   // wave base in floats (1024B)

  float acc[8][8];
#pragma unroll
  for (int i2 = 0; i2 < 8; ++i2) {
    float bv0 = 0.f;
    if (!QM) {
      int o = o0 + ((i2 < 4) ? (ty * 4 + i2) : (64 + ty * 4 + i2 - 4));
      bv0 = bias[o];
    }
#pragma unroll
    for (int j2 = 0; j2 < 8; ++j2) acc[i2][j2] = bv0;
  }

  float4 areg[4];
  // ---- stage helpers ----
  auto loadA = [&](int kc) {
#pragma unroll
    for (int p = 0; p < 4; ++p) {
      int o = aor + (p << 5);
      float4 v = make_float4(0.f, 0.f, 0.f, 0.f);
      if (!QM) {
        v = *(const float4*)(WP + (size_t)(o0 + o) * KP + kc + acb);
      } else {
        int c = kc + acb;
        if (c <= 256) v = *(const float4*)(w + (size_t)(o0 + o) * 392 + 132 + c);
      }
      areg[p] = v;
    }
  };
  auto writeA = [&](float* A) {
#pragma unroll
    for (int p = 0; p < 4; ++p) {
      int o = aor + (p << 5);
      A[(acb + 0) * ALD + o] = areg[p].x;
      A[(acb + 1) * ALD + o] = areg[p].y;
      A[(acb + 2) * ALD + o] = areg[p].z;
      A[(acb + 3) * ALD + o] = areg[p].w;
    }
  };
  auto issueB = [&](int kc, float* Bdst) {
#pragma unroll
    for (int p = 0; p < 4; ++p) {
      int cc = brow + (p << 3);
      int gc = kc + cc;
      float* ldst = Bdst + (p << 10) + wvf;   // wave-uniform base; lane spreads +4*lane
      if (!QM) {
        if (gc < Cc)
          async_cp16(x + ((size_t)(b * Tt + tstep) * Cc + gc) * Nn + n0 + bcol, ldst);
      } else {
        if (gc < 4)
          async_cp16(x + ((size_t)(b * Tt + tp) * Cc + gc) * Nn + n0 + bcol, ldst);
        else if (gc < 260)
          async_cp16(hT + ((size_t)b * HID + (gc - 4)) * Nn + n0 + bcol, ldst);
      }
    }
  };
  auto compute = [&](const float* A, const float* B) {
    float4 a0 = *(const float4*)(A + ty * 4);
    float4 a1 = *(const float4*)(A + 64 + ty * 4);
    float4 b0 = *(const float4*)(B + tx * 4);
    float4 b1 = *(const float4*)(B + 64 + tx * 4);
#pragma unroll
    for (int kk = 0; kk < 32; ++kk) {
      float4 na0, na1, nb0, nb1;
      if (kk < 31) {
        na0 = *(const float4*)(A + (kk + 1) * ALD + ty * 4);
        na1 = *(const float4*)(A + (kk + 1) * ALD + 64 + ty * 4);
        nb0 = *(const float4*)(B + (kk + 1) * BLD + tx * 4);
        nb1 = *(const float4*)(B + (kk + 1) * BLD + 64 + tx * 4);
      }
      float av[8] = {a0.x, a0.y, a0.z, a0.w, a1.x, a1.y, a1.z, a1.w};
      float bw[8] = {b0.x, b0.y, b0.z, b0.w, b1.x, b1.y, b1.z, b1.w};
#pragma unroll
      for (int i2 = 0; i2 < 8; ++i2)
#pragma unroll
        for (int j2 = 0; j2 < 8; ++j2)
          acc[i2][j2] = __fmaf_rn(av[i2], bw[j2], acc[i2][j2]);
      if (kk < 31) { a0 = na0; a1 = na1; b0 = nb0; b1 = nb1; }
    }
  };

  // ---- prologue: stage chunk 0 into buffer 0 ----
  loadA(0);
  issueB(0, Bbuf);
  writeA(Abuf);
  __syncthreads();   // compiler drains vmcnt before s_barrier -> DMA landed
  int buf = 0;
  for (int ch = 0; ch < nch; ++ch) {
    int nb = buf ^ 1;
    if (ch + 1 < nch) {
      loadA((ch + 1) << 5);
      issueB((ch + 1) << 5, Bbuf + nb * (32 * BLD));
    }
    compute(Abuf + buf * (32 * ALD), Bbuf + buf * (32 * BLD));
    if (ch + 1 < nch) writeA(Abuf + nb * (32 * ALD));
    __syncthreads();
    buf = nb;
  }

#pragma unroll
  for (int j2 = 0; j2 < 8; ++j2) {
    int j = n0 + ((j2 < 4) ? (tx * 4 + j2) : (64 + tx * 4 + j2 - 4));
    float* row = outp + ((size_t)b * Nn + j) * G4 + o0;
    *(float4*)(row + ty * 4)      = make_float4(acc[0][j2], acc[1][j2], acc[2][j2], acc[3][j2]);
    *(float4*)(row + 64 + ty * 4) = make_float4(acc[4][j2], acc[5][j2], acc[6][j2], acc[7][j2]);
  }
}

// Dispatch1: blocks [0,128) = Q(t) (critical path), [128,256) = P(t+1).
__global__ __launch_bounds__(256) void gemm_qp(const float* __restrict__ x,
                                               const float* __restrict__ w,
                                               const float* __restrict__ WP,
                                               const float* __restrict__ hT,
                                               const float* __restrict__ bias,
                                               float* __restrict__ Qb,
                                               float* __restrict__ Pnext, int t) {
  __shared__ float Abuf[2 * 32 * ALD];
  __shared__ float Bbuf[2 * 32 * BLD];
  if (blockIdx.x < 128) {
    gemm_tile_v3<true>(blockIdx.x, t, x, w, nullptr, hT, nullptr, Qb, Abuf, Bbuf);
  } else if (t + 1 < Tt) {
    gemm_tile_v3<false>(blockIdx.x - 128, t + 1, x, nullptr, WP, nullptr, bias, Pnext, Abuf, Bbuf);
  }
}

// P(0) prologue
__global__ __launch_bounds__(256) void gemm_p_first(const float* __restrict__ x,
                                                    const float* __restrict__ WP,
                                                    const float* __restrict__ bias,
                                                    float* __restrict__ Pb) {
  __shared__ float Abuf[2 * 32 * ALD];
  __shared__ float Bbuf[2 * 32 * BLD];
  gemm_tile_v3<false>(blockIdx.x, 0, x, nullptr, WP, nullptr, bias, Pb, Abuf, Bbuf);
}

// ---------------------------------------------------------------------------
__device__ __forceinline__ float sigm(float v) { return 1.f / (1.f + __expf(-v)); }
__device__ __forceinline__ float tanh_f(float v) { return 1.f - 2.f / (__expf(2.f * v) + 1.f); }

__global__ __launch_bounds__(256) void lstm_point(const float* __restrict__ Pb,
                                                  const float* __restrict__ Qb,
                                                  const float* __restrict__ cprev,
                                                  const int* __restrict__ gi,
                                                  float* __restrict__ ccur,
                                                  float* __restrict__ hT,
                                                  float* __restrict__ out, int t) {
  int b = blockIdx.x >> 9;
  int n = blockIdx.x & 511;
  int hc = threadIdx.x;
  const float* pr = Pb + ((size_t)b * Nn + n) * G4;
  float pi = pr[hc], pf = pr[HID + hc], po = pr[2 * HID + hc], pg = pr[3 * HID + hc];
  const int* gr = gi + ((size_t)(b * Tt + t) * Nn + n) * KNB;
  float hmax = -3.4e38f, cmax = -3.4e38f;
#pragma unroll
  for (int k = 0; k < KNB; ++k) {
    int j = gr[k];
    const float* qr = Qb + ((size_t)b * Nn + j) * G4;
    float gi_ = pi + qr[hc];
    float gf_ = pf + qr[HID + hc];
    float go_ = po + qr[2 * HID + hc];
    float gg_ = pg + qr[3 * HID + hc];
    float cg = cprev[((size_t)b * Nn + j) * HID + hc];
    float iv = sigm(gi_), fv = sigm(gf_), ov = sigm(go_);
    float gv = tanh_f(gg_);
    float cn = __fmaf_rn(fv, cg, iv * gv);
    float hn = ov * tanh_f(cn);
    hmax = fmaxf(hmax, hn);
    cmax = fmaxf(cmax, cn);
  }
  ccur[((size_t)b * Nn + n) * HID + hc] = cmax;
  hT[((size_t)b * HID + hc) * Nn + n] = hmax;
  out[((size_t)(b * Tt + t) * OUTC + 4 + hc) * Nn + n] = hmax;
}

// ---------------------------------------------------------------------------
__global__ __launch_bounds__(256) void pos_copy(const float* __restrict__ x,
                                                float* __restrict__ out) {
  int i = blockIdx.x * 256 + threadIdx.x;  // B*T*4*N = 262144
  int n = i & 511;
  int c = (i >> 9) & 3;
  int bt = i >> 11;
  out[((size_t)bt * OUTC + c) * Nn + n] = x[((size_t)bt * Cc + c) * Nn + n];
}

__global__ __launch_bounds__(256) void finalize(const float* __restrict__ hT,
                                                const float* __restrict__ cfin,
                                                float* __restrict__ out) {
  int i = blockIdx.x * 256 + threadIdx.x;  // < 524288
  out[OFF_HF + i] = hT[i];
  int n = i & 511;
  int rest = i >> 9;
  int hc = rest & 255;
  int b = rest >> 8;
  out[OFF_CF + i] = cfin[((size_t)b * Nn + n) * HID + hc];
}

// ---------------------------------------------------------------------------
extern "C" void kernel_launch(void* const* d_in, const int* in_sizes, int n_in,
                              void* d_out, int out_size, void* d_ws, size_t ws_size,
                              hipStream_t stream) {
  const float* x    = (const float*)d_in[0];
  const float* w    = (const float*)d_in[1];
  const float* bias = (const float*)d_in[2];
  float* out = (float*)d_out;

  float* WP  = (float*)d_ws;
  int*   gi  = (int*)(WP + WP_SZ);
  float* hT  = (float*)(gi + GI_SZ);
  float* c0  = hT + HT_SZ;
  float* c1  = c0 + CB_SZ;
  float* Pb0 = c1 + CB_SZ;
  float* Pb1 = Pb0 + PQ_SZ;
  float* Qb  = Pb1 + PQ_SZ;

  init_kernel<<<4736, 256, 0, stream>>>(w, WP, hT, c0);
  knn_kernel<<<1024, 256, 0, stream>>>(x, gi, out + OFF_GI);
  pos_copy<<<1024, 256, 0, stream>>>(x, out);
  gemm_p_first<<<128, 256, 0, stream>>>(x, WP, bias, Pb0);

  float* cp = c0;
  float* cn = c1;
  for (int t = 0; t < Tt; ++t) {
    float* Pcur  = (t & 1) ? Pb1 : Pb0;
    float* Pnext = (t & 1) ? Pb0 : Pb1;
    gemm_qp<<<256, 256, 0, stream>>>(x, w, WP, hT, bias, Qb, Pnext, t);
    lstm_point<<<2048, 256, 0, stream>>>(Pcur, Qb, cp, gi, cn, hT, out, t);
    float* tmp = cp; cp = cn; cn = tmp;
  }
  finalize<<<2048, 256, 0, stream>>>(hT, cp, out);
}

// Round 6
// 2757.538 us; speedup vs baseline: 1.7114x; 1.7114x over previous
//
#include <hip/hip_runtime.h>
#include <stdint.h>

// Problem constants
#define Bb   4
#define Tt   32
#define Cc   132
#define Nn   512
#define HID  256
#define KNB  16
#define OUTC 260           // 4 + HID
#define G4   1024          // 4*HID gate rows
#define KP   160           // padded K for P-gemm (132 -> 160, 5 chunks of 32)
#define LDT  132           // LDS tile row stride (128 + 4 pad)

// Workspace layout (element counts)
#define WP_SZ (1024*KP)          // 163840 f
#define GI_SZ (Bb*Tt*Nn*KNB)     // 1048576 i
#define HT_SZ (Bb*HID*Nn)        // 524288 f
#define CB_SZ (Bb*Nn*HID)        // 524288 f
#define PQ_SZ (Bb*Nn*G4)         // 2097152 f

// Output offsets (floats): layer_output, h_f, c_f, group_ind
#define OFF_HF 17039360
#define OFF_CF 17563648
#define OFF_GI 18087936

// ---------------------------------------------------------------------------
// init: build W_P = w[:, :132] with first-4 columns reduced by w[:,132:136],
// zero-padded to K=160; zero h (transposed layout) and c buffer 0.
__global__ __launch_bounds__(256) void init_kernel(const float* __restrict__ w,
                                                   float* __restrict__ WP,
                                                   float* __restrict__ hT,
                                                   float* __restrict__ c0) {
  int i = blockIdx.x * 256 + threadIdx.x;
  if (i < WP_SZ) {
    int o = i / KP, c = i % KP;
    float v = 0.f;
    if (c < Cc) {
      v = w[(size_t)o * 392 + c];
      if (c < 4) v -= w[(size_t)o * 392 + 132 + c];
    }
    WP[i] = v;
  } else if (i < WP_SZ + HT_SZ) {
    hT[i - WP_SZ] = 0.f;
  } else if (i < WP_SZ + HT_SZ + CB_SZ) {
    c0[i - WP_SZ - HT_SZ] = 0.f;
  }
}

// ---------------------------------------------------------------------------
// KNN (R1 version, measured 172us, 0 bank conflicts): per (b,t), one thread
// per query, full 512-candidate scan, packed u64 compare-swap top-16.
// Exact fp32 replication of the XLA arithmetic; ties -> lower index.
__global__ __launch_bounds__(256) void knn_kernel(const float* __restrict__ x,
                                                  int* __restrict__ gi,
                                                  float* __restrict__ gi_f) {
  int bt = blockIdx.x >> 1;
  int b = bt >> 5, t = bt & 31;
  int tr = t > 0 ? t - 1 : 0;
  __shared__ float r0[Nn], r1[Nn], r2[Nn], rr[Nn];
  const float* xr = x + (size_t)(b * Tt + tr) * Cc * Nn;
  for (int m = threadIdx.x; m < Nn; m += 256) {
    float a0 = xr[m], a1 = xr[Nn + m], a2 = xr[2 * Nn + m];
    r0[m] = a0; r1[m] = a1; r2[m] = a2;
    rr[m] = __fadd_rn(__fadd_rn(__fmul_rn(a0, a0), __fmul_rn(a1, a1)), __fmul_rn(a2, a2));
  }
  __syncthreads();
  int n = ((blockIdx.x & 1) << 8) + threadIdx.x;
  const float* xq = x + (size_t)(b * Tt + t) * Cc * Nn;
  float q0 = xq[n], q1 = xq[Nn + n], q2 = xq[2 * Nn + n];
  float qq = __fadd_rn(__fadd_rn(__fmul_rn(q0, q0), __fmul_rn(q1, q1)), __fmul_rn(q2, q2));
  unsigned long long best[KNB];
#pragma unroll
  for (int s = 0; s < KNB; ++s) best[s] = 0xFFFFFFFFFFFFFFFFull;
  for (int m = 0; m < Nn; ++m) {
    float in = __fmaf_rn(q2, r2[m], __fmaf_rn(q1, r1[m], __fmul_rn(q0, r0[m])));
    float d2 = __fsub_rn(__fadd_rn(qq, rr[m]), __fmul_rn(2.0f, in));
    unsigned int bits = __float_as_uint(d2);
    unsigned int key = (bits & 0x80000000u) ? ~bits : (bits | 0x80000000u);
    unsigned long long cand = ((unsigned long long)key << 32) | (unsigned int)m;
#pragma unroll
    for (int s = 0; s < KNB; ++s) {
      bool sw = cand < best[s];
      unsigned long long lo = sw ? cand : best[s];
      cand = sw ? best[s] : cand;
      best[s] = lo;
    }
  }
  size_t ob = ((size_t)(b * Tt + t) * Nn + n) * KNB;
#pragma unroll
  for (int s = 0; s < KNB; ++s) {
    int idx = (int)(best[s] & 0xFFFFFFFFull);
    gi[ob + s] = idx;
    gi_f[ob + s] = (float)idx;
  }
}

// ---------------------------------------------------------------------------
// Fused P/Q GEMM (R1 version, known-good). Blocks 0..127: P = W_P @ X_t + b.
// Blocks 128..255: Q = w[:,132:392] @ [pp_tp ; h].
// 128x128 tile, 256 threads, 8x8 micro with split 4+4 fragments.
__global__ __launch_bounds__(256) void gemm_pq(const float* __restrict__ x,
                                               const float* __restrict__ w,
                                               const float* __restrict__ WP,
                                               const float* __restrict__ hT,
                                               const float* __restrict__ bias,
                                               float* __restrict__ Pb,
                                               float* __restrict__ Qb, int t) {
  const bool qm = blockIdx.x >= 128;
  const int bid = blockIdx.x & 127;
  const int b = bid >> 5;
  const int to = (bid >> 2) & 7;
  const int tn = bid & 3;
  const int o0 = to << 7, n0 = tn << 7;
  __shared__ float At[32 * LDT];
  __shared__ float Bt[32 * LDT];
  const int tid = threadIdx.x;
  const int tx = tid & 15, ty = tid >> 4;
  float acc[8][8];
#pragma unroll
  for (int i2 = 0; i2 < 8; ++i2) {
    float bv0 = 0.f;
    if (!qm) {
      int o = o0 + ((i2 < 4) ? (ty * 4 + i2) : (64 + ty * 4 + i2 - 4));
      bv0 = bias[o];
    }
#pragma unroll
    for (int j2 = 0; j2 < 8; ++j2) acc[i2][j2] = bv0;
  }
  const int tp = (t > 0) ? (t - 1) : 0;
  const int nch = qm ? 9 : 5;
  const int acb = (tid & 7) * 4;   // A stage: c offset within chunk
  const int aor = tid >> 3;        // A stage: o row
  const int bj4 = (tid & 31) * 4;  // B stage: j offset
  const int bcr = tid >> 5;        // B stage: c row
  for (int ch = 0; ch < nch; ++ch) {
    const int kc = ch << 5;
    // stage A transposed: At[cc][o]
#pragma unroll
    for (int p = 0; p < 4; ++p) {
      int o = aor + (p << 5);
      float4 v = make_float4(0.f, 0.f, 0.f, 0.f);
      if (!qm) {
        v = *(const float4*)(WP + (size_t)(o0 + o) * KP + kc + acb);
      } else {
        int c = kc + acb;
        if (c <= 256) v = *(const float4*)(w + (size_t)(o0 + o) * 392 + 132 + c);
      }
      At[(acb + 0) * LDT + o] = v.x;
      At[(acb + 1) * LDT + o] = v.y;
      At[(acb + 2) * LDT + o] = v.z;
      At[(acb + 3) * LDT + o] = v.w;
    }
    // stage B direct: Bt[cc][j]
#pragma unroll
    for (int p = 0; p < 4; ++p) {
      int cc = bcr + (p << 3);
      int c = kc + cc;
      float4 v = make_float4(0.f, 0.f, 0.f, 0.f);
      if (!qm) {
        if (c < Cc) v = *(const float4*)(x + ((size_t)(b * Tt + t) * Cc + c) * Nn + n0 + bj4);
      } else {
        if (c < 4)        v = *(const float4*)(x + ((size_t)(b * Tt + tp) * Cc + c) * Nn + n0 + bj4);
        else if (c < 260) v = *(const float4*)(hT + ((size_t)b * HID + (c - 4)) * Nn + n0 + bj4);
      }
      *(float4*)(Bt + cc * LDT + bj4) = v;
    }
    __syncthreads();
#pragma unroll
    for (int kk = 0; kk < 32; ++kk) {
      const float* ar = At + kk * LDT;
      const float* br = Bt + kk * LDT;
      float4 a0 = *(const float4*)(ar + ty * 4);
      float4 a1 = *(const float4*)(ar + 64 + ty * 4);
      float4 b0 = *(const float4*)(br + tx * 4);
      float4 b1 = *(const float4*)(br + 64 + tx * 4);
      float av[8] = {a0.x, a0.y, a0.z, a0.w, a1.x, a1.y, a1.z, a1.w};
      float bw[8] = {b0.x, b0.y, b0.z, b0.w, b1.x, b1.y, b1.z, b1.w};
#pragma unroll
      for (int i2 = 0; i2 < 8; ++i2)
#pragma unroll
        for (int j2 = 0; j2 < 8; ++j2)
          acc[i2][j2] = __fmaf_rn(av[i2], bw[j2], acc[i2][j2]);
    }
    __syncthreads();
  }
  float* outp = qm ? Qb : Pb;
#pragma unroll
  for (int j2 = 0; j2 < 8; ++j2) {
    int j = n0 + ((j2 < 4) ? (tx * 4 + j2) : (64 + tx * 4 + j2 - 4));
    float* row = outp + ((size_t)b * Nn + j) * G4 + o0;
    *(float4*)(row + ty * 4)      = make_float4(acc[0][j2], acc[1][j2], acc[2][j2], acc[3][j2]);
    *(float4*)(row + 64 + ty * 4) = make_float4(acc[4][j2], acc[5][j2], acc[6][j2], acc[7][j2]);
  }
}

// ---------------------------------------------------------------------------
__device__ __forceinline__ float sigm(float v) { return 1.f / (1.f + __expf(-v)); }
__device__ __forceinline__ float tanh_f(float v) { return 1.f - 2.f / (__expf(2.f * v) + 1.f); }

// Pointwise LSTM + max-pool over 16 neighbors.
// SINGLE CHANGE vs R1: XCD-aware block decode. Assuming round-robin
// workgroup->XCD (blockIdx % 8), all blocks of batch b land on XCDs {2b,2b+1},
// so each XCD's gather working set is Qb[b] (2.1MB) + c[b] (0.5MB) < 4MB L2.
// Bijective (b,n) remap; per-(b,n) arithmetic identical -> bit-exact.
__global__ __launch_bounds__(256) void lstm_point(const float* __restrict__ Pb,
                                                  const float* __restrict__ Qb,
                                                  const float* __restrict__ cprev,
                                                  const int* __restrict__ gi,
                                                  float* __restrict__ ccur,
                                                  float* __restrict__ hT,
                                                  float* __restrict__ out, int t) {
  int i = blockIdx.x;
  int xcd = i & 7;
  int b = xcd >> 1;
  int n = ((i >> 3) << 1) | (xcd & 1);
  int hc = threadIdx.x;
  const float* pr = Pb + ((size_t)b * Nn + n) * G4;
  float pi = pr[hc], pf = pr[HID + hc], po = pr[2 * HID + hc], pg = pr[3 * HID + hc];
  const int* gr = gi + ((size_t)(b * Tt + t) * Nn + n) * KNB;
  float hmax = -3.4e38f, cmax = -3.4e38f;
#pragma unroll
  for (int k = 0; k < KNB; ++k) {
    int j = gr[k];
    const float* qr = Qb + ((size_t)b * Nn + j) * G4;
    float gi_ = pi + qr[hc];
    float gf_ = pf + qr[HID + hc];
    float go_ = po + qr[2 * HID + hc];
    float gg_ = pg + qr[3 * HID + hc];
    float cg = cprev[((size_t)b * Nn + j) * HID + hc];
    float iv = sigm(gi_), fv = sigm(gf_), ov = sigm(go_);
    float gv = tanh_f(gg_);
    float cn = __fmaf_rn(fv, cg, iv * gv);
    float hn = ov * tanh_f(cn);
    hmax = fmaxf(hmax, hn);
    cmax = fmaxf(cmax, cn);
  }
  ccur[((size_t)b * Nn + n) * HID + hc] = cmax;
  hT[((size_t)b * HID + hc) * Nn + n] = hmax;                      // for next-step Q-gemm
  out[((size_t)(b * Tt + t) * OUTC + 4 + hc) * Nn + n] = hmax;     // layer_output h part
}

// ---------------------------------------------------------------------------
// layer_output position channels (all t)
__global__ __launch_bounds__(256) void pos_copy(const float* __restrict__ x,
                                                float* __restrict__ out) {
  int i = blockIdx.x * 256 + threadIdx.x;  // B*T*4*N = 262144
  int n = i & 511;
  int c = (i >> 9) & 3;
  int bt = i >> 11;
  out[((size_t)bt * OUTC + c) * Nn + n] = x[((size_t)bt * Cc + c) * Nn + n];
}

// h_f (flat copy of hT) and c_f (transpose of final c buffer)
__global__ __launch_bounds__(256) void finalize(const float* __restrict__ hT,
                                                const float* __restrict__ cfin,
                                                float* __restrict__ out) {
  int i = blockIdx.x * 256 + threadIdx.x;  // < 524288
  out[OFF_HF + i] = hT[i];
  int n = i & 511;
  int rest = i >> 9;
  int hc = rest & 255;
  int b = rest >> 8;
  out[OFF_CF + i] = cfin[((size_t)b * Nn + n) * HID + hc];
}

// ---------------------------------------------------------------------------
extern "C" void kernel_launch(void* const* d_in, const int* in_sizes, int n_in,
                              void* d_out, int out_size, void* d_ws, size_t ws_size,
                              hipStream_t stream) {
  const float* x    = (const float*)d_in[0];
  const float* w    = (const float*)d_in[1];
  const float* bias = (const float*)d_in[2];
  float* out = (float*)d_out;

  float* WP = (float*)d_ws;
  int*   gi = (int*)(WP + WP_SZ);
  float* hT = (float*)(gi + GI_SZ);
  float* c0 = hT + HT_SZ;
  float* c1 = c0 + CB_SZ;
  float* Pb = c1 + CB_SZ;
  float* Qb = Pb + PQ_SZ;

  init_kernel<<<4736, 256, 0, stream>>>(w, WP, hT, c0);
  knn_kernel<<<256, 256, 0, stream>>>(x, gi, out + OFF_GI);
  pos_copy<<<1024, 256, 0, stream>>>(x, out);

  float* cp = c0;
  float* cn = c1;
  for (int t = 0; t < Tt; ++t) {
    gemm_pq<<<256, 256, 0, stream>>>(x, w, WP, hT, bias, Pb, Qb, t);
    lstm_point<<<2048, 256, 0, stream>>>(Pb, Qb, cp, gi, cn, hT, out, t);
    float* tmp = cp; cp = cn; cn = tmp;
  }
  finalize<<<2048, 256, 0, stream>>>(hT, cp, out);
}

// Round 7
// 2331.333 us; speedup vs baseline: 2.0242x; 1.1828x over previous
//
#include <hip/hip_runtime.h>
#include <stdint.h>

// Problem constants
#define Bb   4
#define Tt   32
#define Cc   132
#define Nn   512
#define HID  256
#define KNB  16
#define OUTC 260           // 4 + HID
#define G4   1024          // 4*HID gate rows
#define KP   160           // padded K for P-gemm (132 -> 160, 5 chunks of 32)
#define LDT  132           // LDS tile row stride (128 + 4 pad)

// Workspace layout (element counts)
#define WP_SZ (1024*KP)          // 163840 f
#define GI_SZ (Bb*Tt*Nn*KNB)     // 1048576 i
#define HT_SZ (Bb*HID*Nn)        // 524288 f
#define CB_SZ (Bb*Nn*HID)        // 524288 f
#define PQ_SZ (Bb*Nn*G4)         // 2097152 f

// Output offsets (floats): layer_output, h_f, c_f, group_ind
#define OFF_HF 17039360
#define OFF_CF 17563648
#define OFF_GI 18087936

// ---------------------------------------------------------------------------
// init: build W_P = w[:, :132] with first-4 columns reduced by w[:,132:136],
// zero-padded to K=160; zero h (transposed layout) and c buffer 0.
__global__ __launch_bounds__(256) void init_kernel(const float* __restrict__ w,
                                                   float* __restrict__ WP,
                                                   float* __restrict__ hT,
                                                   float* __restrict__ c0) {
  int i = blockIdx.x * 256 + threadIdx.x;
  if (i < WP_SZ) {
    int o = i / KP, c = i % KP;
    float v = 0.f;
    if (c < Cc) {
      v = w[(size_t)o * 392 + c];
      if (c < 4) v -= w[(size_t)o * 392 + 132 + c];
    }
    WP[i] = v;
  } else if (i < WP_SZ + HT_SZ) {
    hT[i - WP_SZ] = 0.f;
  } else if (i < WP_SZ + HT_SZ + CB_SZ) {
    c0[i - WP_SZ - HT_SZ] = 0.f;
  }
}

// ---------------------------------------------------------------------------
// KNN (R1 version, measured 170us, 0 bank conflicts): per (b,t), one thread
// per query, full 512-candidate scan, packed u64 compare-swap top-16.
// Exact fp32 replication of the XLA arithmetic; ties -> lower index.
__global__ __launch_bounds__(256) void knn_kernel(const float* __restrict__ x,
                                                  int* __restrict__ gi,
                                                  float* __restrict__ gi_f) {
  int bt = blockIdx.x >> 1;
  int b = bt >> 5, t = bt & 31;
  int tr = t > 0 ? t - 1 : 0;
  __shared__ float r0[Nn], r1[Nn], r2[Nn], rr[Nn];
  const float* xr = x + (size_t)(b * Tt + tr) * Cc * Nn;
  for (int m = threadIdx.x; m < Nn; m += 256) {
    float a0 = xr[m], a1 = xr[Nn + m], a2 = xr[2 * Nn + m];
    r0[m] = a0; r1[m] = a1; r2[m] = a2;
    rr[m] = __fadd_rn(__fadd_rn(__fmul_rn(a0, a0), __fmul_rn(a1, a1)), __fmul_rn(a2, a2));
  }
  __syncthreads();
  int n = ((blockIdx.x & 1) << 8) + threadIdx.x;
  const float* xq = x + (size_t)(b * Tt + t) * Cc * Nn;
  float q0 = xq[n], q1 = xq[Nn + n], q2 = xq[2 * Nn + n];
  float qq = __fadd_rn(__fadd_rn(__fmul_rn(q0, q0), __fmul_rn(q1, q1)), __fmul_rn(q2, q2));
  unsigned long long best[KNB];
#pragma unroll
  for (int s = 0; s < KNB; ++s) best[s] = 0xFFFFFFFFFFFFFFFFull;
  for (int m = 0; m < Nn; ++m) {
    float in = __fmaf_rn(q2, r2[m], __fmaf_rn(q1, r1[m], __fmul_rn(q0, r0[m])));
    float d2 = __fsub_rn(__fadd_rn(qq, rr[m]), __fmul_rn(2.0f, in));
    unsigned int bits = __float_as_uint(d2);
    unsigned int key = (bits & 0x80000000u) ? ~bits : (bits | 0x80000000u);
    unsigned long long cand = ((unsigned long long)key << 32) | (unsigned int)m;
#pragma unroll
    for (int s = 0; s < KNB; ++s) {
      bool sw = cand < best[s];
      unsigned long long lo = sw ? cand : best[s];
      cand = sw ? best[s] : cand;
      best[s] = lo;
    }
  }
  size_t ob = ((size_t)(b * Tt + t) * Nn + n) * KNB;
#pragma unroll
  for (int s = 0; s < KNB; ++s) {
    int idx = (int)(best[s] & 0xFFFFFFFFull);
    gi[ob + s] = idx;
    gi_f[ob + s] = (float)idx;
  }
}

// ---------------------------------------------------------------------------
// Fused P/Q GEMM. Blocks 0..127: P = W_P @ X_t + b. Blocks 128..255: Q.
// 128x128 tile. SINGLE CHANGE vs R6: 512 threads (8 waves = 2 waves/SIMD,
// was 256 threads = 1 wave/SIMD), micro-tile 8(o)x4(n). Same K-chunk order,
// same per-output FMA chain -> bitwise identical to R1/R6.
__global__ __launch_bounds__(512) void gemm_pq(const float* __restrict__ x,
                                               const float* __restrict__ w,
                                               const float* __restrict__ WP,
                                               const float* __restrict__ hT,
                                               const float* __restrict__ bias,
                                               float* __restrict__ Pb,
                                               float* __restrict__ Qb, int t) {
  const bool qm = blockIdx.x >= 128;
  const int bid = blockIdx.x & 127;
  const int b = bid >> 5;
  const int to = (bid >> 2) & 7;
  const int tn = bid & 3;
  const int o0 = to << 7, n0 = tn << 7;
  __shared__ float At[32 * LDT];
  __shared__ float Bt[32 * LDT];
  const int tid = threadIdx.x;
  const int tx = tid & 31, ty = tid >> 5;   // tx: n-group 0..31, ty: o-group 0..15
  float acc[8][4];
#pragma unroll
  for (int i2 = 0; i2 < 8; ++i2) {
    float bv0 = 0.f;
    if (!qm) {
      int o = o0 + ((i2 < 4) ? (ty * 4 + i2) : (64 + ty * 4 + i2 - 4));
      bv0 = bias[o];
    }
#pragma unroll
    for (int j2 = 0; j2 < 4; ++j2) acc[i2][j2] = bv0;
  }
  const int tp = (t > 0) ? (t - 1) : 0;
  const int nch = qm ? 9 : 5;
  // A stage: 512 threads x 2 float4 = 1024 float4 (32c x 128o transposed)
  const int acb = (tid & 3) * 4;   // c offset {0,4,8,12}; +p*16
  const int aor = tid >> 2;        // o row 0..127
  // B stage: 512 threads x 2 float4 (32c x 128j direct)
  const int bj4 = (tid & 31) * 4;  // j offset
  const int bcr = tid >> 5;        // c row 0..15; +p*16
  for (int ch = 0; ch < nch; ++ch) {
    const int kc = ch << 5;
    // stage A transposed: At[cc][o]
#pragma unroll
    for (int p = 0; p < 2; ++p) {
      int c = acb + (p << 4);
      int gc = kc + c;
      float4 v = make_float4(0.f, 0.f, 0.f, 0.f);
      if (!qm) {
        v = *(const float4*)(WP + (size_t)(o0 + aor) * KP + gc);
      } else {
        if (gc <= 256) v = *(const float4*)(w + (size_t)(o0 + aor) * 392 + 132 + gc);
      }
      At[(c + 0) * LDT + aor] = v.x;
      At[(c + 1) * LDT + aor] = v.y;
      At[(c + 2) * LDT + aor] = v.z;
      At[(c + 3) * LDT + aor] = v.w;
    }
    // stage B direct: Bt[cc][j]
#pragma unroll
    for (int p = 0; p < 2; ++p) {
      int cc = bcr + (p << 4);
      int c = kc + cc;
      float4 v = make_float4(0.f, 0.f, 0.f, 0.f);
      if (!qm) {
        if (c < Cc) v = *(const float4*)(x + ((size_t)(b * Tt + t) * Cc + c) * Nn + n0 + bj4);
      } else {
        if (c < 4)        v = *(const float4*)(x + ((size_t)(b * Tt + tp) * Cc + c) * Nn + n0 + bj4);
        else if (c < 260) v = *(const float4*)(hT + ((size_t)b * HID + (c - 4)) * Nn + n0 + bj4);
      }
      *(float4*)(Bt + cc * LDT + bj4) = v;
    }
    __syncthreads();
#pragma unroll
    for (int kk = 0; kk < 32; ++kk) {
      const float* ar = At + kk * LDT;
      const float* br = Bt + kk * LDT;
      float4 a0 = *(const float4*)(ar + ty * 4);
      float4 a1 = *(const float4*)(ar + 64 + ty * 4);
      float4 b0 = *(const float4*)(br + tx * 4);
      float av[8] = {a0.x, a0.y, a0.z, a0.w, a1.x, a1.y, a1.z, a1.w};
      float bw[4] = {b0.x, b0.y, b0.z, b0.w};
#pragma unroll
      for (int i2 = 0; i2 < 8; ++i2)
#pragma unroll
        for (int j2 = 0; j2 < 4; ++j2)
          acc[i2][j2] = __fmaf_rn(av[i2], bw[j2], acc[i2][j2]);
    }
    __syncthreads();
  }
  float* outp = qm ? Qb : Pb;
#pragma unroll
  for (int j2 = 0; j2 < 4; ++j2) {
    int j = n0 + tx * 4 + j2;
    float* row = outp + ((size_t)b * Nn + j) * G4 + o0;
    *(float4*)(row + ty * 4)      = make_float4(acc[0][j2], acc[1][j2], acc[2][j2], acc[3][j2]);
    *(float4*)(row + 64 + ty * 4) = make_float4(acc[4][j2], acc[5][j2], acc[6][j2], acc[7][j2]);
  }
}

// ---------------------------------------------------------------------------
__device__ __forceinline__ float sigm(float v) { return 1.f / (1.f + __expf(-v)); }
__device__ __forceinline__ float tanh_f(float v) { return 1.f - 2.f / (__expf(2.f * v) + 1.f); }

// Pointwise LSTM + max-pool over 16 neighbors. XCD-aware decode (R6, +116us).
__global__ __launch_bounds__(256) void lstm_point(const float* __restrict__ Pb,
                                                  const float* __restrict__ Qb,
                                                  const float* __restrict__ cprev,
                                                  const int* __restrict__ gi,
                                                  float* __restrict__ ccur,
                                                  float* __restrict__ hT,
                                                  float* __restrict__ out, int t) {
  int i = blockIdx.x;
  int xcd = i & 7;
  int b = xcd >> 1;
  int n = ((i >> 3) << 1) | (xcd & 1);
  int hc = threadIdx.x;
  const float* pr = Pb + ((size_t)b * Nn + n) * G4;
  float pi = pr[hc], pf = pr[HID + hc], po = pr[2 * HID + hc], pg = pr[3 * HID + hc];
  const int* gr = gi + ((size_t)(b * Tt + t) * Nn + n) * KNB;
  float hmax = -3.4e38f, cmax = -3.4e38f;
#pragma unroll
  for (int k = 0; k < KNB; ++k) {
    int j = gr[k];
    const float* qr = Qb + ((size_t)b * Nn + j) * G4;
    float gi_ = pi + qr[hc];
    float gf_ = pf + qr[HID + hc];
    float go_ = po + qr[2 * HID + hc];
    float gg_ = pg + qr[3 * HID + hc];
    float cg = cprev[((size_t)b * Nn + j) * HID + hc];
    float iv = sigm(gi_), fv = sigm(gf_), ov = sigm(go_);
    float gv = tanh_f(gg_);
    float cn = __fmaf_rn(fv, cg, iv * gv);
    float hn = ov * tanh_f(cn);
    hmax = fmaxf(hmax, hn);
    cmax = fmaxf(cmax, cn);
  }
  ccur[((size_t)b * Nn + n) * HID + hc] = cmax;
  hT[((size_t)b * HID + hc) * Nn + n] = hmax;                      // for next-step Q-gemm
  out[((size_t)(b * Tt + t) * OUTC + 4 + hc) * Nn + n] = hmax;     // layer_output h part
}

// ---------------------------------------------------------------------------
// layer_output position channels (all t)
__global__ __launch_bounds__(256) void pos_copy(const float* __restrict__ x,
                                                float* __restrict__ out) {
  int i = blockIdx.x * 256 + threadIdx.x;  // B*T*4*N = 262144
  int n = i & 511;
  int c = (i >> 9) & 3;
  int bt = i >> 11;
  out[((size_t)bt * OUTC + c) * Nn + n] = x[((size_t)bt * Cc + c) * Nn + n];
}

// h_f (flat copy of hT) and c_f (transpose of final c buffer)
__global__ __launch_bounds__(256) void finalize(const float* __restrict__ hT,
                                                const float* __restrict__ cfin,
                                                float* __restrict__ out) {
  int i = blockIdx.x * 256 + threadIdx.x;  // < 524288
  out[OFF_HF + i] = hT[i];
  int n = i & 511;
  int rest = i >> 9;
  int hc = rest & 255;
  int b = rest >> 8;
  out[OFF_CF + i] = cfin[((size_t)b * Nn + n) * HID + hc];
}

// ---------------------------------------------------------------------------
extern "C" void kernel_launch(void* const* d_in, const int* in_sizes, int n_in,
                              void* d_out, int out_size, void* d_ws, size_t ws_size,
                              hipStream_t stream) {
  const float* x    = (const float*)d_in[0];
  const float* w    = (const float*)d_in[1];
  const float* bias = (const float*)d_in[2];
  float* out = (float*)d_out;

  float* WP = (float*)d_ws;
  int*   gi = (int*)(WP + WP_SZ);
  float* hT = (float*)(gi + GI_SZ);
  float* c0 = hT + HT_SZ;
  float* c1 = c0 + CB_SZ;
  float* Pb = c1 + CB_SZ;
  float* Qb = Pb + PQ_SZ;

  init_kernel<<<4736, 256, 0, stream>>>(w, WP, hT, c0);
  knn_kernel<<<256, 256, 0, stream>>>(x, gi, out + OFF_GI);
  pos_copy<<<1024, 256, 0, stream>>>(x, out);

  float* cp = c0;
  float* cn = c1;
  for (int t = 0; t < Tt; ++t) {
    gemm_pq<<<256, 512, 0, stream>>>(x, w, WP, hT, bias, Pb, Qb, t);
    lstm_point<<<2048, 256, 0, stream>>>(Pb, Qb, cp, gi, cn, hT, out, t);
    float* tmp = cp; cp = cn; cn = tmp;
  }
  finalize<<<2048, 256, 0, stream>>>(hT, cp, out);
}